// Round 4
// baseline (281.650 us; speedup 1.0000x reference)
//
#include <hip/hip_runtime.h>

typedef __bf16 bf16x8 __attribute__((ext_vector_type(8)));
typedef float f32x4 __attribute__((ext_vector_type(4)));
typedef int i32x4 __attribute__((ext_vector_type(4)));

#define T_DIM   2048
#define D_MODEL 2048
#define INNER_D 1024
#define N_HEADS 16
#define D_HEAD  64
#define BATCH   4
#define J_TOK   512

// bf16 1.0 = 0x3F80 in the first ushort; fp32 1.0 -> first ushort 0x0000
__device__ __forceinline__ bool is_bf16(const unsigned short* lnw) {
  return lnw[0] == 0x3F80u;
}

// async global->LDS, 16B per lane (dest must be wave-uniform base + lane*16)
__device__ __forceinline__ void async16(const void* g, void* l) {
  __builtin_amdgcn_global_load_lds(
      (const __attribute__((address_space(1))) void*)g,
      (__attribute__((address_space(3))) void*)l, 16, 0, 0);
}

// ---------------------------------------------------------------------------
// transpose 32x32 tile helper: in[R][C] (bf16|fp32) -> out[C][R] bf16
// ---------------------------------------------------------------------------
__device__ __forceinline__ void transpose_tile(const void* in, __bf16* out,
                                               int R, int C, int r0, int c0,
                                               bool isbf, __bf16 (*t)[33]) {
  const int tx = threadIdx.x & 31, ty = threadIdx.x >> 5;
#pragma unroll
  for (int i = 0; i < 4; ++i) {
    const size_t idx = (size_t)(r0 + ty + i * 8) * C + c0 + tx;
    t[ty + i * 8][tx] = isbf ? ((const __bf16*)in)[idx] : (__bf16)((const float*)in)[idx];
  }
  __syncthreads();
#pragma unroll
  for (int i = 0; i < 4; ++i)
    out[(size_t)(c0 + ty + i * 8) * R + r0 + tx] = t[tx][ty + i * 8];
}

// ---------------------------------------------------------------------------
// 1) prep: scan (4 blocks) | convert media (1024) | T(Wkv) (2048) | T(Wq) (2048)
// ---------------------------------------------------------------------------
__global__ __launch_bounds__(256) void prep_kernel(
    const int* __restrict__ mloc, int* __restrict__ chunk,
    const void* __restrict__ media, __bf16* __restrict__ media_bf,
    const void* __restrict__ Wkv, __bf16* __restrict__ WkvT,
    const void* __restrict__ Wq, __bf16* __restrict__ WqT,
    const unsigned short* __restrict__ lnw) {
  __shared__ int sd[256];
  __shared__ __bf16 t[32][33];
  const bool isbf = is_bf16(lnw);
  const int bid = blockIdx.x;
  const int tid = threadIdx.x;

  if (bid < 4) {
    // ---- scan: cumsum of media_locations -> chunk index ----
    const int b = bid;
    const int base = tid * 8;
    const int* row = mloc + b * T_DIM;
    int v[8];
    int s = 0;
#pragma unroll
    for (int i = 0; i < 8; ++i) { v[i] = (row[base + i] != 0) ? 1 : 0; s += v[i]; }
    sd[tid] = s;
    __syncthreads();
    for (int off = 1; off < 256; off <<= 1) {
      int tv = (tid >= off) ? sd[tid - off] : 0;
      __syncthreads();
      sd[tid] += tv;
      __syncthreads();
    }
    int run = sd[tid] - s;
#pragma unroll
    for (int i = 0; i < 8; ++i) {
      run += v[i];
      chunk[b * T_DIM + base + i] = run - 1;
    }
  } else if (bid < 4 + 1024) {
    // ---- convert media -> bf16 ----
    const size_t i = ((size_t)(bid - 4) * 256 + tid) * 8;
    if (isbf) {
      *(i32x4*)(media_bf + i) = *(const i32x4*)((const __bf16*)media + i);
    } else {
      const float* p = (const float*)media + i;
      f32x4 a = *(const f32x4*)p, b2 = *(const f32x4*)(p + 4);
      bf16x8 o;
#pragma unroll
      for (int j = 0; j < 4; ++j) { o[j] = (__bf16)a[j]; o[4 + j] = (__bf16)b2[j]; }
      *(i32x4*)(media_bf + i) = __builtin_bit_cast(i32x4, o);
    }
  } else if (bid < 4 + 1024 + 2048) {
    // ---- WkvT[2048][1024] = T(Wkv[1024][2048]) ----
    const int idx = bid - (4 + 1024);
    transpose_tile(Wkv, WkvT, 1024, 2048, (idx >> 6) * 32, (idx & 63) * 32, isbf, t);
  } else {
    // ---- WqT[1024][2048] = T(Wq[2048][1024]) ----
    const int idx = bid - (4 + 1024 + 2048);
    transpose_tile(Wq, WqT, 2048, 1024, (idx >> 5) * 32, (idx & 31) * 32, isbf, t);
  }
}

// ---------------------------------------------------------------------------
// 2) standalone transpose for Wout (runs after attn, into dead q region)
// ---------------------------------------------------------------------------
__global__ __launch_bounds__(256) void transpose_kernel(const void* __restrict__ in,
                                                        __bf16* __restrict__ out,
                                                        int R, int C,
                                                        const unsigned short* __restrict__ lnw) {
  __shared__ __bf16 t[32][33];
  transpose_tile(in, out, R, C, blockIdx.y * 32, blockIdx.x * 32, is_bf16(lnw), t);
}

// ---------------------------------------------------------------------------
// 3) LayerNorm: y [8192, 2048] (bf16|fp32) -> yn bf16
// ---------------------------------------------------------------------------
__global__ __launch_bounds__(256) void ln_kernel(const void* __restrict__ yv,
                                                 const void* __restrict__ wv_,
                                                 const void* __restrict__ bv_,
                                                 __bf16* __restrict__ yn) {
  const int row = blockIdx.x;
  const int tid = threadIdx.x;
  const int lane = tid & 63, wave = tid >> 6;
  const bool isbf = is_bf16((const unsigned short*)wv_);
  float xf[8], wf[8], bf[8];
  if (isbf) {
    const __bf16* x = (const __bf16*)yv + (size_t)row * D_MODEL + tid * 8;
    bf16x8 xv = __builtin_bit_cast(bf16x8, *(const i32x4*)x);
    bf16x8 ww = __builtin_bit_cast(bf16x8, *(const i32x4*)((const __bf16*)wv_ + tid * 8));
    bf16x8 bb = __builtin_bit_cast(bf16x8, *(const i32x4*)((const __bf16*)bv_ + tid * 8));
#pragma unroll
    for (int i = 0; i < 8; ++i) { xf[i] = (float)xv[i]; wf[i] = (float)ww[i]; bf[i] = (float)bb[i]; }
  } else {
    const float* x = (const float*)yv + (size_t)row * D_MODEL + tid * 8;
    f32x4 a0 = *(const f32x4*)x, a1 = *(const f32x4*)(x + 4);
    const float* wp = (const float*)wv_ + tid * 8;
    f32x4 w0 = *(const f32x4*)wp, w1 = *(const f32x4*)(wp + 4);
    const float* bp = (const float*)bv_ + tid * 8;
    f32x4 b0 = *(const f32x4*)bp, b1 = *(const f32x4*)(bp + 4);
#pragma unroll
    for (int i = 0; i < 4; ++i) {
      xf[i] = a0[i]; xf[4 + i] = a1[i];
      wf[i] = w0[i]; wf[4 + i] = w1[i];
      bf[i] = b0[i]; bf[4 + i] = b1[i];
    }
  }
  float s = 0.f, s2 = 0.f;
#pragma unroll
  for (int i = 0; i < 8; ++i) { s += xf[i]; s2 += xf[i] * xf[i]; }
#pragma unroll
  for (int off = 32; off > 0; off >>= 1) { s += __shfl_xor(s, off); s2 += __shfl_xor(s2, off); }
  __shared__ float red[4][2];
  if (lane == 0) { red[wave][0] = s; red[wave][1] = s2; }
  __syncthreads();
  s = red[0][0] + red[1][0] + red[2][0] + red[3][0];
  s2 = red[0][1] + red[1][1] + red[2][1] + red[3][1];
  const float mu = s * (1.f / D_MODEL);
  const float var = s2 * (1.f / D_MODEL) - mu * mu;
  const float rstd = rsqrtf(var + 1e-5f);
  bf16x8 outv;
#pragma unroll
  for (int i = 0; i < 8; ++i)
    outv[i] = (__bf16)((xf[i] - mu) * rstd * wf[i] + bf[i]);
  *(i32x4*)(yn + (size_t)row * D_MODEL + tid * 8) = __builtin_bit_cast(i32x4, outv);
}

// ---------------------------------------------------------------------------
// 4) GEMM: C[M,N] = alpha * A[M,K] @ Bt[N,K]^T, bf16, BK=64 (32 MFMA/barrier).
//    128x128 tile, global_load_lds width-16, 8-slot rotate swizzle (2-way free).
//    Used for the kv-GEMM only.
// ---------------------------------------------------------------------------
__global__ __launch_bounds__(256) void gemm_bt(const __bf16* __restrict__ A,
                                               const __bf16* __restrict__ Bt,
                                               void* __restrict__ Cv,
                                               int M, int N, int K, float alpha,
                                               int cF, const unsigned short* __restrict__ lnw) {
  __shared__ __bf16 As[128 * 64];
  __shared__ __bf16 Bs[128 * 64];
  const int tid = threadIdx.x;
  const int wave = tid >> 6, lane = tid & 63;
  const int wrow = wave & 1, wcol = wave >> 1;
  const int bm0 = blockIdx.y * 128, bn0 = blockIdx.x * 128;
  const int lr = lane & 15, qd = lane >> 4;

  // staging decode: unit u -> row r=u>>3, pos p=u&7 holds chunk j=(p-r)&7
  int r_[4], j_[4];
#pragma unroll
  for (int i = 0; i < 4; ++i) {
    int u = i * 256 + tid;
    r_[i] = u >> 3;
    j_[i] = ((u & 7) - (u >> 3)) & 7;
  }

  f32x4 acc[4][4] = {};

  for (int k0 = 0; k0 < K; k0 += 64) {
#pragma unroll
    for (int i = 0; i < 4; ++i)
      async16(A + (size_t)(bm0 + r_[i]) * K + k0 + j_[i] * 8, &As[(i * 256 + tid) * 8]);
#pragma unroll
    for (int i = 0; i < 4; ++i)
      async16(Bt + (size_t)(bn0 + r_[i]) * K + k0 + j_[i] * 8, &Bs[(i * 256 + tid) * 8]);
    __syncthreads();

#pragma unroll
    for (int ks = 0; ks < 2; ++ks) {
      bf16x8 af[4], bf[4];
#pragma unroll
      for (int mt = 0; mt < 4; ++mt) {
        int row = wrow * 64 + mt * 16 + lr;
        int c = ks * 4 + qd;
        af[mt] = *(const bf16x8*)&As[row * 64 + ((c + row) & 7) * 8];
      }
#pragma unroll
      for (int nt = 0; nt < 4; ++nt) {
        int row = wcol * 64 + nt * 16 + lr;
        int c = ks * 4 + qd;
        bf[nt] = *(const bf16x8*)&Bs[row * 64 + ((c + row) & 7) * 8];
      }
#pragma unroll
      for (int mt = 0; mt < 4; ++mt)
#pragma unroll
        for (int nt = 0; nt < 4; ++nt)
          acc[mt][nt] =
              __builtin_amdgcn_mfma_f32_16x16x32_bf16(af[mt], bf[nt], acc[mt][nt], 0, 0, 0);
    }
    __syncthreads();
  }

  const int r0w = qd * 4, cn = lr;
  const bool f32out = cF && !is_bf16(lnw);
  if (!f32out) {
    __bf16* C = (__bf16*)Cv;
#pragma unroll
    for (int mt = 0; mt < 4; ++mt)
#pragma unroll
      for (int nt = 0; nt < 4; ++nt)
#pragma unroll
        for (int r = 0; r < 4; ++r) {
          int grow = bm0 + wrow * 64 + mt * 16 + r0w + r;
          int gcol = bn0 + wcol * 64 + nt * 16 + cn;
          C[(size_t)grow * N + gcol] = (__bf16)(acc[mt][nt][r] * alpha);
        }
  } else {
    float* C = (float*)Cv;
#pragma unroll
    for (int mt = 0; mt < 4; ++mt)
#pragma unroll
      for (int nt = 0; nt < 4; ++nt)
#pragma unroll
        for (int r = 0; r < 4; ++r) {
          int grow = bm0 + wrow * 64 + mt * 16 + r0w + r;
          int gcol = bn0 + wcol * 64 + nt * 16 + cn;
          C[(size_t)grow * N + gcol] = acc[mt][nt][r] * alpha;
        }
  }
}

// ---------------------------------------------------------------------------
// shared helper: rotate-swizzled LDS fragment read.
// half = [128 rows][64 bf16]; chunk slot = ((cb>>4) + row) & 7 (proven 0
// bank conflicts: 8 consecutive rows cover all 8 16B slots -> 2 lanes/slot).
// ---------------------------------------------------------------------------
__device__ __forceinline__ bf16x8 fragld(const __bf16* half, int row, int cb) {
  const int slot = ((cb >> 4) + row) & 7;
  return *(const bf16x8*)((const char*)half + row * 128 + slot * 16);
}

// XCD-aware bijective block swizzle; requires (gridDim.x*gridDim.y) % 8 == 0
__device__ __forceinline__ int xcd_swz(int gx, int gy) {
  int bid = blockIdx.y * gx + blockIdx.x;
  const int nwg = gx * gy;
  return (bid & 7) * (nwg >> 3) + (bid >> 3);
}

// ---------------------------------------------------------------------------
// 4b) 256x128 deep-pipelined GEMM (both big GEMMs).
//     512 threads = 8 waves (4M x 2N), per-wave 64x64 output, BK=64.
//     2 phases/K-tile, 16 MFMA each (template granularity, 4 barriers/tile).
//     LDS: 3 slots x {A0,A1,B} x 16 KiB = 144 KiB -> tile t+2 staged during
//     tile t; steady-state wait is vmcnt(6) (t+2's 6 loads stay in flight,
//     t+1's loads get a FULL K-tile of latency cover).
//     Slot lifetime: slot (t+2)%3 was last read in tile t-1, whose closing
//     barrier precedes this tile's STG -> no race.
//     Grid (N/128, M/256), nwg % 8 == 0 for the XCD swizzle.
// ---------------------------------------------------------------------------
__global__ __launch_bounds__(512, 2) void gemm256x128d(const __bf16* __restrict__ A,
                                                       const __bf16* __restrict__ Bt,
                                                       void* __restrict__ Cv,
                                                       int M, int N, int K, float alpha,
                                                       int cF, const unsigned short* __restrict__ lnw) {
  __shared__ __bf16 lds[9][128 * 64];  // [slot*3 + {A0,A1,B}] = 144 KiB
  const int tid = threadIdx.x;
  const int wave = tid >> 6, lane = tid & 63;
  const int wm = wave >> 1, wn = wave & 1;  // 4M x 2N wave grid; per-wave 64x64
  const int lr = lane & 15, qd = lane >> 4;
  const int gx = gridDim.x;
  const int bid = xcd_swz(gx, gridDim.y);
  const int bm0 = (bid / gx) * 256, bn0 = (bid % gx) * 128;
  const int nt = K >> 6;

  // staging decode (rotate swizzle): physical 16B unit u -> LDS row r = u>>3,
  // slot p = u&7 holds logical chunk j = (p - r) & 7 -> source col j*8 elems.
  int rS[2], cS[2];
#pragma unroll
  for (int q = 0; q < 2; ++q) {
    int u = q * 512 + tid;
    rS[q] = u >> 3;
    cS[q] = (((u & 7) - (u >> 3)) & 7) * 8;
  }
  const __bf16* sA0[2];
  const __bf16* sA1[2];
  const __bf16* sB[2];
#pragma unroll
  for (int q = 0; q < 2; ++q) {
    sA0[q] = A + (size_t)(bm0 + rS[q]) * K + cS[q];
    sA1[q] = A + (size_t)(bm0 + 128 + rS[q]) * K + cS[q];
    sB[q]  = Bt + (size_t)(bn0 + rS[q]) * K + cS[q];
  }
  const int d0 = tid * 16, d1 = (512 + tid) * 16;

#define STG(sp, half, k)                         \
  do {                                           \
    async16((sp)[0] + (k), (char*)(half) + d0);  \
    async16((sp)[1] + (k), (char*)(half) + d1);  \
  } while (0)

  // ---- prologue: stage tiles 0 and 1 fully; vmcnt(6) => tile0 complete ----
  STG(sA0, lds[0], 0);
  STG(sA1, lds[1], 0);
  STG(sB,  lds[2], 0);
  if (nt > 1) {
    STG(sA0, lds[3], 64);
    STG(sA1, lds[4], 64);
    STG(sB,  lds[5], 64);
    asm volatile("s_waitcnt vmcnt(6)" ::: "memory");
  } else {
    asm volatile("s_waitcnt vmcnt(0)" ::: "memory");
  }
  __builtin_amdgcn_sched_barrier(0);
  __builtin_amdgcn_s_barrier();

  f32x4 acc[4][4] = {};
  bf16x8 af[2][2], bf[4][2];
  const int arow = (wm & 1) * 64, brow = wn * 64;

  int cur = 0;
  for (int t = 0; t < nt; ++t) {
    const __bf16* myA = lds[cur * 3 + (wm >> 1)];
    const __bf16* myB = lds[cur * 3 + 2];
    int nxt = cur + 1; if (nxt == 3) nxt = 0;
    int n2  = nxt + 1; if (n2 == 3) n2 = 0;      // slot for tile t+2
    const int k2 = (t + 2) << 6;

    // ---------------- phase 1: M-rows 0..31 x all N ----------------
#pragma unroll
    for (int m = 0; m < 2; ++m)
#pragma unroll
      for (int ks = 0; ks < 2; ++ks)
        af[m][ks] = fragld(myA, arow + m * 16 + lr, ks * 64 + qd * 16);
#pragma unroll
    for (int n = 0; n < 4; ++n)
#pragma unroll
      for (int ks = 0; ks < 2; ++ks)
        bf[n][ks] = fragld(myB, brow + ((n & 1) * 32 >= 64 ? 0 : 0) + n * 16 + lr, ks * 64 + qd * 16);
    if (t + 2 < nt) {
      STG(sA0, lds[n2 * 3 + 0], k2);
      STG(sA1, lds[n2 * 3 + 1], k2);
    }
    __builtin_amdgcn_s_barrier();
    __builtin_amdgcn_s_setprio(1);
#pragma unroll
    for (int m = 0; m < 2; ++m)
#pragma unroll
      for (int n = 0; n < 4; ++n)
#pragma unroll
        for (int ks = 0; ks < 2; ++ks)
          acc[m][n] =
              __builtin_amdgcn_mfma_f32_16x16x32_bf16(af[m][ks], bf[n][ks], acc[m][n], 0, 0, 0);
    __builtin_amdgcn_s_setprio(0);
    __builtin_amdgcn_s_barrier();

    // ---------------- phase 2: M-rows 32..63 x all N ----------------
#pragma unroll
    for (int m = 0; m < 2; ++m)
#pragma unroll
      for (int ks = 0; ks < 2; ++ks)
        af[m][ks] = fragld(myA, arow + 32 + m * 16 + lr, ks * 64 + qd * 16);
    if (t + 2 < nt) STG(sB, lds[n2 * 3 + 2], k2);
    __builtin_amdgcn_s_barrier();
    __builtin_amdgcn_s_setprio(1);
#pragma unroll
    for (int m = 0; m < 2; ++m)
#pragma unroll
      for (int n = 0; n < 4; ++n)
#pragma unroll
        for (int ks = 0; ks < 2; ++ks)
          acc[2 + m][n] = __builtin_amdgcn_mfma_f32_16x16x32_bf16(af[m][ks], bf[n][ks],
                                                                  acc[2 + m][n], 0, 0, 0);
    __builtin_amdgcn_s_setprio(0);
    // steady state: 12 outstanding (t+1's 6 + t+2's 6); drain the 6 oldest
    // (t+1 becomes ready), keep t+2's 6 in flight across the barrier.
    if (t + 2 < nt) {
      asm volatile("s_waitcnt vmcnt(6)" ::: "memory");
    } else {
      asm volatile("s_waitcnt vmcnt(0)" ::: "memory");
    }
    __builtin_amdgcn_sched_barrier(0);
    __builtin_amdgcn_s_barrier();
    cur = nxt;
  }
#undef STG

  // ---- epilogue: C write ----
  const bool f32out = cF && !is_bf16(lnw);
  if (!f32out) {
    __bf16* C = (__bf16*)Cv;
#pragma unroll
    for (int m = 0; m < 4; ++m)
#pragma unroll
      for (int n = 0; n < 4; ++n)
#pragma unroll
        for (int r = 0; r < 4; ++r) {
          int grow = bm0 + wm * 64 + m * 16 + qd * 4 + r;
          int gcol = bn0 + wn * 64 + n * 16 + lr;
          C[(size_t)grow * N + gcol] = (__bf16)(acc[m][n][r] * alpha);
        }
  } else {
    float* C = (float*)Cv;
#pragma unroll
    for (int m = 0; m < 4; ++m)
#pragma unroll
      for (int n = 0; n < 4; ++n)
#pragma unroll
        for (int r = 0; r < 4; ++r) {
          int grow = bm0 + wm * 64 + m * 16 + qd * 4 + r;
          int gcol = bn0 + wn * 64 + n * 16 + lr;
          C[(size_t)grow * N + gcol] = acc[m][n][r] * alpha;
        }
  }
}

// ---------------------------------------------------------------------------
// 5) MFMA attention (unchanged — verified correct)
// ---------------------------------------------------------------------------
__global__ __launch_bounds__(256) void attn_kernel(const __bf16* __restrict__ q,
                                                   const __bf16* __restrict__ kv,
                                                   const int* __restrict__ chunk,
                                                   __bf16* __restrict__ attn) {
  const int h = blockIdx.x, tile = blockIdx.y, b = blockIdx.z;
  const int tid = threadIdx.x, wave = tid >> 6, lane = tid & 63;
  const int lr = lane & 15, qd = lane >> 4;
  __shared__ __bf16 Vt[64][72];
  __shared__ __bf16 P[4][64][72];

  int c = chunk[b * T_DIM + tile * 256];
  c = c < 0 ? 0 : (c > 7 ? 7 : c);
  const size_t kvbase = ((size_t)b * J_TOK + c * 64) * (2 * INNER_D);

#pragma unroll
  for (int it = 0; it < 2; ++it) {
    int u = it * 256 + tid;
    int key = u & 63, d0 = (u >> 6) * 8;
    bf16x8 v = __builtin_bit_cast(
        bf16x8, *(const i32x4*)(kv + kvbase + (size_t)key * (2 * INNER_D) + INNER_D + h * 64 + d0));
#pragma unroll
    for (int j = 0; j < 8; ++j) Vt[d0 + j][key] = v[j];
  }
  __syncthreads();

  const size_t qbase = ((size_t)(b * T_DIM + tile * 256 + wave * 64)) * INNER_D + h * 64;
  f32x4 acc[4][4] = {};
#pragma unroll
  for (int ks = 0; ks < 2; ++ks) {
    bf16x8 af[4], bf[4];
#pragma unroll
    for (int mt = 0; mt < 4; ++mt)
      af[mt] = __builtin_bit_cast(
          bf16x8, *(const i32x4*)(q + qbase + (size_t)(mt * 16 + lr) * INNER_D + ks * 32 + qd * 8));
#pragma unroll
    for (int nt = 0; nt < 4; ++nt)
      bf[nt] = __builtin_bit_cast(
          bf16x8,
          *(const i32x4*)(kv + kvbase + (size_t)(nt * 16 + lr) * (2 * INNER_D) + h * 64 + ks * 32 + qd * 8));
#pragma unroll
    for (int mt = 0; mt < 4; ++mt)
#pragma unroll
      for (int nt = 0; nt < 4; ++nt)
        acc[mt][nt] =
            __builtin_amdgcn_mfma_f32_16x16x32_bf16(af[mt], bf[nt], acc[mt][nt], 0, 0, 0);
  }

#pragma unroll
  for (int mt = 0; mt < 4; ++mt) {
#pragma unroll
    for (int r = 0; r < 4; ++r) {
      float v0 = acc[mt][0][r], v1 = acc[mt][1][r], v2 = acc[mt][2][r], v3 = acc[mt][3][r];
      float mx = fmaxf(fmaxf(v0, v1), fmaxf(v2, v3));
      mx = fmaxf(mx, __shfl_xor(mx, 1));
      mx = fmaxf(mx, __shfl_xor(mx, 2));
      mx = fmaxf(mx, __shfl_xor(mx, 4));
      mx = fmaxf(mx, __shfl_xor(mx, 8));
      float p0 = __expf(v0 - mx), p1 = __expf(v1 - mx), p2 = __expf(v2 - mx), p3 = __expf(v3 - mx);
      float l = p0 + p1 + p2 + p3;
      l += __shfl_xor(l, 1);
      l += __shfl_xor(l, 2);
      l += __shfl_xor(l, 4);
      l += __shfl_xor(l, 8);
      const float rl = 1.0f / l;
      const int row = mt * 16 + qd * 4 + r;
      P[wave][row][lr]      = (__bf16)(p0 * rl);
      P[wave][row][16 + lr] = (__bf16)(p1 * rl);
      P[wave][row][32 + lr] = (__bf16)(p2 * rl);
      P[wave][row][48 + lr] = (__bf16)(p3 * rl);
    }
  }
  __syncthreads();

  f32x4 oc[4][4] = {};
#pragma unroll
  for (int ks = 0; ks < 2; ++ks) {
    bf16x8 af[4], bv[4];
#pragma unroll
    for (int mt = 0; mt < 4; ++mt)
      af[mt] = *(const bf16x8*)&P[wave][mt * 16 + lr][ks * 32 + qd * 8];
#pragma unroll
    for (int nt = 0; nt < 4; ++nt)
      bv[nt] = *(const bf16x8*)&Vt[nt * 16 + lr][ks * 32 + qd * 8];
#pragma unroll
    for (int mt = 0; mt < 4; ++mt)
#pragma unroll
      for (int nt = 0; nt < 4; ++nt)
        oc[mt][nt] =
            __builtin_amdgcn_mfma_f32_16x16x32_bf16(af[mt], bv[nt], oc[mt][nt], 0, 0, 0);
  }

#pragma unroll
  for (int mt = 0; mt < 4; ++mt)
#pragma unroll
    for (int nt = 0; nt < 4; ++nt)
#pragma unroll
      for (int r = 0; r < 4; ++r) {
        int row = mt * 16 + qd * 4 + r;
        int col = nt * 16 + lr;
        attn[((size_t)(b * T_DIM + tile * 256 + wave * 64 + row)) * INNER_D + h * 64 + col] =
            (__bf16)oc[mt][nt][r];
      }
}

// ---------------------------------------------------------------------------
// launch (7 dispatches)
// ---------------------------------------------------------------------------
extern "C" void kernel_launch(void* const* d_in, const int* in_sizes, int n_in,
                              void* d_out, int out_size, void* d_ws, size_t ws_size,
                              hipStream_t stream) {
  const void* y     = d_in[0];
  const void* media = d_in[1];
  const int*  mloc  = (const int*)d_in[2];
  const unsigned short* lnw = (const unsigned short*)d_in[3];
  const void* lnb   = d_in[4];
  const void* Wq    = d_in[5];
  const void* Wkv   = d_in[6];
  const void* Wout  = d_in[7];

  char* ws = (char*)d_ws;
  int*    chunk    = (int*)ws;                              // 32 KB
  __bf16* yn       = (__bf16*)(ws + 65536);                 // 33.55 MB [8192,2048]
  __bf16* media_bf = yn;                                    // alias (dead before LN)
  __bf16* WkvT     = (__bf16*)(ws + 65536 + 4194304);       // alias in yn (dead before LN)
  __bf16* attn     = yn;                                    // alias (yn dead after q-gemm)
  __bf16* q        = (__bf16*)(ws + 65536 + 33554432);      // 16.78 MB
  __bf16* WoutT    = q;                                     // alias (q dead after attn)
  __bf16* kv       = (__bf16*)(ws + 65536 + 33554432 + 16777216);           // 8.39 MB
  __bf16* WqT      = (__bf16*)(ws + 65536 + 33554432 + 16777216 + 8388608); // 4.19 MB
  // total: ~63.0 MB (proven budget)

  // 1) prep: scan | media->bf16 | T(Wkv) | T(Wq)
  prep_kernel<<<4 + 1024 + 2048 + 2048, 256, 0, stream>>>(
      mloc, chunk, media, media_bf, Wkv, WkvT, Wq, WqT, lnw);
  // 2) kv = media_bf [2048,1024] @ Wkv -> [2048,2048]
  gemm_bt<<<dim3(16, 16), 256, 0, stream>>>(media_bf, WkvT, kv, 2048, 2048, 1024, 1.0f, 0, lnw);
  // 3) LN (clobbers media_bf/WkvT aliases - both dead)
  ln_kernel<<<BATCH * T_DIM, 256, 0, stream>>>(y, lnw, lnb, yn);
  // 4) q = yn [8192,2048] @ Wq * 0.125 -> [8192,1024]  (deep 256x128)
  gemm256x128d<<<dim3(8, 32), 512, 0, stream>>>(yn, WqT, q, 8192, 1024, 2048, 0.125f, 0, lnw);
  // 5) attention
  attn_kernel<<<dim3(16, 8, 4), 256, 0, stream>>>(q, kv, chunk, attn);
  // 6) WoutT [2048][1024] = T(Wout [1024][2048]) into dead q region
  transpose_kernel<<<dim3(64, 32), 256, 0, stream>>>(Wout, WoutT, 1024, 2048, lnw);
  // 7) out = attn [8192,1024] @ Wout -> [8192,2048]  (deep 256x128)
  gemm256x128d<<<dim3(16, 32), 512, 0, stream>>>(attn, WoutT, d_out, 8192, 2048, 1024, 1.0f, 1, lnw);
}

// Round 5
// 270.128 us; speedup vs baseline: 1.0427x; 1.0427x over previous
//
#include <hip/hip_runtime.h>

typedef __bf16 bf16x8 __attribute__((ext_vector_type(8)));
typedef float f32x4 __attribute__((ext_vector_type(4)));
typedef int i32x4 __attribute__((ext_vector_type(4)));

#define T_DIM   2048
#define D_MODEL 2048
#define INNER_D 1024
#define N_HEADS 16
#define D_HEAD  64
#define BATCH   4
#define J_TOK   512

// bf16 1.0 = 0x3F80 in the first ushort; fp32 1.0 -> first ushort 0x0000
__device__ __forceinline__ bool is_bf16(const unsigned short* lnw) {
  return lnw[0] == 0x3F80u;
}

// async global->LDS, 16B per lane (dest must be wave-uniform base + lane*16)
__device__ __forceinline__ void async16(const void* g, void* l) {
  __builtin_amdgcn_global_load_lds(
      (const __attribute__((address_space(1))) void*)g,
      (__attribute__((address_space(3))) void*)l, 16, 0, 0);
}

// ---------------------------------------------------------------------------
// transpose 32x32 tile helper: in[R][C] (bf16|fp32) -> out[C][R] bf16
// ---------------------------------------------------------------------------
__device__ __forceinline__ void transpose_tile(const void* in, __bf16* out,
                                               int R, int C, int r0, int c0,
                                               bool isbf, __bf16 (*t)[33]) {
  const int tx = threadIdx.x & 31, ty = threadIdx.x >> 5;
#pragma unroll
  for (int i = 0; i < 4; ++i) {
    const size_t idx = (size_t)(r0 + ty + i * 8) * C + c0 + tx;
    t[ty + i * 8][tx] = isbf ? ((const __bf16*)in)[idx] : (__bf16)((const float*)in)[idx];
  }
  __syncthreads();
#pragma unroll
  for (int i = 0; i < 4; ++i)
    out[(size_t)(c0 + ty + i * 8) * R + r0 + tx] = t[tx][ty + i * 8];
}

// ---------------------------------------------------------------------------
// LayerNorm one row (callable from fused prep or standalone kernel)
// ---------------------------------------------------------------------------
__device__ __forceinline__ void ln_row(int row, const void* yv, const void* wv_,
                                       const void* bv_, __bf16* yn) {
  const int tid = threadIdx.x;
  const int lane = tid & 63, wave = tid >> 6;
  const bool isbf = is_bf16((const unsigned short*)wv_);
  float xf[8], wf[8], bf[8];
  if (isbf) {
    const __bf16* x = (const __bf16*)yv + (size_t)row * D_MODEL + tid * 8;
    bf16x8 xv = __builtin_bit_cast(bf16x8, *(const i32x4*)x);
    bf16x8 ww = __builtin_bit_cast(bf16x8, *(const i32x4*)((const __bf16*)wv_ + tid * 8));
    bf16x8 bb = __builtin_bit_cast(bf16x8, *(const i32x4*)((const __bf16*)bv_ + tid * 8));
#pragma unroll
    for (int i = 0; i < 8; ++i) { xf[i] = (float)xv[i]; wf[i] = (float)ww[i]; bf[i] = (float)bb[i]; }
  } else {
    const float* x = (const float*)yv + (size_t)row * D_MODEL + tid * 8;
    f32x4 a0 = *(const f32x4*)x, a1 = *(const f32x4*)(x + 4);
    const float* wp = (const float*)wv_ + tid * 8;
    f32x4 w0 = *(const f32x4*)wp, w1 = *(const f32x4*)(wp + 4);
    const float* bp = (const float*)bv_ + tid * 8;
    f32x4 b0 = *(const f32x4*)bp, b1 = *(const f32x4*)(bp + 4);
#pragma unroll
    for (int i = 0; i < 4; ++i) {
      xf[i] = a0[i]; xf[4 + i] = a1[i];
      wf[i] = w0[i]; wf[4 + i] = w1[i];
      bf[i] = b0[i]; bf[4 + i] = b1[i];
    }
  }
  float s = 0.f, s2 = 0.f;
#pragma unroll
  for (int i = 0; i < 8; ++i) { s += xf[i]; s2 += xf[i] * xf[i]; }
#pragma unroll
  for (int off = 32; off > 0; off >>= 1) { s += __shfl_xor(s, off); s2 += __shfl_xor(s2, off); }
  __shared__ float red[4][2];
  if (lane == 0) { red[wave][0] = s; red[wave][1] = s2; }
  __syncthreads();
  s = red[0][0] + red[1][0] + red[2][0] + red[3][0];
  s2 = red[0][1] + red[1][1] + red[2][1] + red[3][1];
  const float mu = s * (1.f / D_MODEL);
  const float var = s2 * (1.f / D_MODEL) - mu * mu;
  const float rstd = rsqrtf(var + 1e-5f);
  bf16x8 outv;
#pragma unroll
  for (int i = 0; i < 8; ++i)
    outv[i] = (__bf16)((xf[i] - mu) * rstd * wf[i] + bf[i]);
  *(i32x4*)(yn + (size_t)row * D_MODEL + tid * 8) = __builtin_bit_cast(i32x4, outv);
}

// ---------------------------------------------------------------------------
// 1) prep: scan (4) | convert media (1024) | T(Wkv) (2048) | T(Wq) (2048)
//    [+ ext: T(Wout) (2048) | LN (8192)]
// ---------------------------------------------------------------------------
__global__ __launch_bounds__(256) void prep_kernel(
    const int* __restrict__ mloc, int* __restrict__ chunk,
    const void* __restrict__ media, __bf16* __restrict__ media_bf,
    const void* __restrict__ Wkv, __bf16* __restrict__ WkvT,
    const void* __restrict__ Wq, __bf16* __restrict__ WqT,
    const void* __restrict__ Wout, __bf16* __restrict__ WoutT,
    const void* __restrict__ y, const void* __restrict__ lnb,
    __bf16* __restrict__ yn, int nWout,
    const unsigned short* __restrict__ lnw) {
  __shared__ int sd[256];
  __shared__ __bf16 t[32][33];
  const bool isbf = is_bf16(lnw);
  const int tid = threadIdx.x;
  int r = blockIdx.x;

  if (r < 4) {
    // ---- scan: cumsum of media_locations -> chunk index ----
    const int b = r;
    const int base = tid * 8;
    const int* row = mloc + b * T_DIM;
    int v[8];
    int s = 0;
#pragma unroll
    for (int i = 0; i < 8; ++i) { v[i] = (row[base + i] != 0) ? 1 : 0; s += v[i]; }
    sd[tid] = s;
    __syncthreads();
    for (int off = 1; off < 256; off <<= 1) {
      int tv = (tid >= off) ? sd[tid - off] : 0;
      __syncthreads();
      sd[tid] += tv;
      __syncthreads();
    }
    int run = sd[tid] - s;
#pragma unroll
    for (int i = 0; i < 8; ++i) {
      run += v[i];
      chunk[b * T_DIM + base + i] = run - 1;
    }
    return;
  }
  r -= 4;
  if (r < 1024) {
    // ---- convert media -> bf16 ----
    const size_t i = ((size_t)r * 256 + tid) * 8;
    if (isbf) {
      *(i32x4*)(media_bf + i) = *(const i32x4*)((const __bf16*)media + i);
    } else {
      const float* p = (const float*)media + i;
      f32x4 a = *(const f32x4*)p, b2 = *(const f32x4*)(p + 4);
      bf16x8 o;
#pragma unroll
      for (int j = 0; j < 4; ++j) { o[j] = (__bf16)a[j]; o[4 + j] = (__bf16)b2[j]; }
      *(i32x4*)(media_bf + i) = __builtin_bit_cast(i32x4, o);
    }
    return;
  }
  r -= 1024;
  if (r < 2048) {
    // ---- WkvT[2048][1024] = T(Wkv[1024][2048]) ----
    transpose_tile(Wkv, WkvT, 1024, 2048, (r >> 6) * 32, (r & 63) * 32, isbf, t);
    return;
  }
  r -= 2048;
  if (r < 2048) {
    // ---- WqT[1024][2048] = T(Wq[2048][1024]) ----
    transpose_tile(Wq, WqT, 2048, 1024, (r >> 5) * 32, (r & 31) * 32, isbf, t);
    return;
  }
  r -= 2048;
  if (r < nWout) {
    // ---- WoutT[2048][1024] = T(Wout[1024][2048]) ----
    transpose_tile(Wout, WoutT, 1024, 2048, (r >> 6) * 32, (r & 63) * 32, isbf, t);
    return;
  }
  r -= nWout;
  // ---- LayerNorm rows (ext path only) ----
  ln_row(r, y, lnw, lnb, yn);
}

// ---------------------------------------------------------------------------
// 2) standalone transpose for Wout (fallback path: runs after attn)
// ---------------------------------------------------------------------------
__global__ __launch_bounds__(256) void transpose_kernel(const void* __restrict__ in,
                                                        __bf16* __restrict__ out,
                                                        int R, int C,
                                                        const unsigned short* __restrict__ lnw) {
  __shared__ __bf16 t[32][33];
  transpose_tile(in, out, R, C, blockIdx.y * 32, blockIdx.x * 32, is_bf16(lnw), t);
}

// ---------------------------------------------------------------------------
// 3) standalone LayerNorm (fallback path)
// ---------------------------------------------------------------------------
__global__ __launch_bounds__(256) void ln_kernel(const void* __restrict__ yv,
                                                 const void* __restrict__ wv_,
                                                 const void* __restrict__ bv_,
                                                 __bf16* __restrict__ yn) {
  ln_row(blockIdx.x, yv, wv_, bv_, yn);
}

// ---------------------------------------------------------------------------
// 4) GEMM: C[M,N] = alpha * A[M,K] @ Bt[N,K]^T, bf16, BK=64 (32 MFMA/barrier).
//    128x128 tile, global_load_lds width-16, 8-slot rotate swizzle.
//    Used for the kv-GEMM only.
// ---------------------------------------------------------------------------
__global__ __launch_bounds__(256) void gemm_bt(const __bf16* __restrict__ A,
                                               const __bf16* __restrict__ Bt,
                                               void* __restrict__ Cv,
                                               int M, int N, int K, float alpha,
                                               int cF, const unsigned short* __restrict__ lnw) {
  __shared__ __bf16 As[128 * 64];
  __shared__ __bf16 Bs[128 * 64];
  const int tid = threadIdx.x;
  const int wave = tid >> 6, lane = tid & 63;
  const int wrow = wave & 1, wcol = wave >> 1;
  const int bm0 = blockIdx.y * 128, bn0 = blockIdx.x * 128;
  const int lr = lane & 15, qd = lane >> 4;

  int r_[4], j_[4];
#pragma unroll
  for (int i = 0; i < 4; ++i) {
    int u = i * 256 + tid;
    r_[i] = u >> 3;
    j_[i] = ((u & 7) - (u >> 3)) & 7;
  }

  f32x4 acc[4][4] = {};

  for (int k0 = 0; k0 < K; k0 += 64) {
#pragma unroll
    for (int i = 0; i < 4; ++i)
      async16(A + (size_t)(bm0 + r_[i]) * K + k0 + j_[i] * 8, &As[(i * 256 + tid) * 8]);
#pragma unroll
    for (int i = 0; i < 4; ++i)
      async16(Bt + (size_t)(bn0 + r_[i]) * K + k0 + j_[i] * 8, &Bs[(i * 256 + tid) * 8]);
    __syncthreads();

#pragma unroll
    for (int ks = 0; ks < 2; ++ks) {
      bf16x8 af[4], bf[4];
#pragma unroll
      for (int mt = 0; mt < 4; ++mt) {
        int row = wrow * 64 + mt * 16 + lr;
        int c = ks * 4 + qd;
        af[mt] = *(const bf16x8*)&As[row * 64 + ((c + row) & 7) * 8];
      }
#pragma unroll
      for (int nt = 0; nt < 4; ++nt) {
        int row = wcol * 64 + nt * 16 + lr;
        int c = ks * 4 + qd;
        bf[nt] = *(const bf16x8*)&Bs[row * 64 + ((c + row) & 7) * 8];
      }
#pragma unroll
      for (int mt = 0; mt < 4; ++mt)
#pragma unroll
        for (int nt = 0; nt < 4; ++nt)
          acc[mt][nt] =
              __builtin_amdgcn_mfma_f32_16x16x32_bf16(af[mt], bf[nt], acc[mt][nt], 0, 0, 0);
    }
    __syncthreads();
  }

  const int r0w = qd * 4, cn = lr;
  const bool f32out = cF && !is_bf16(lnw);
  if (!f32out) {
    __bf16* C = (__bf16*)Cv;
#pragma unroll
    for (int mt = 0; mt < 4; ++mt)
#pragma unroll
      for (int nt = 0; nt < 4; ++nt)
#pragma unroll
        for (int r = 0; r < 4; ++r) {
          int grow = bm0 + wrow * 64 + mt * 16 + r0w + r;
          int gcol = bn0 + wcol * 64 + nt * 16 + cn;
          C[(size_t)grow * N + gcol] = (__bf16)(acc[mt][nt][r] * alpha);
        }
  } else {
    float* C = (float*)Cv;
#pragma unroll
    for (int mt = 0; mt < 4; ++mt)
#pragma unroll
      for (int nt = 0; nt < 4; ++nt)
#pragma unroll
        for (int r = 0; r < 4; ++r) {
          int grow = bm0 + wrow * 64 + mt * 16 + r0w + r;
          int gcol = bn0 + wcol * 64 + nt * 16 + cn;
          C[(size_t)grow * N + gcol] = acc[mt][nt][r] * alpha;
        }
  }
}

// ---------------------------------------------------------------------------
// shared helper: rotate-swizzled LDS fragment read.
// half = [128 rows][64 bf16]; chunk slot = ((cb>>4) + row) & 7 (proven 0
// bank conflicts: 8 consecutive rows cover all 8 16B slots -> 2 lanes/slot).
// ---------------------------------------------------------------------------
__device__ __forceinline__ bf16x8 fragld(const __bf16* half, int row, int cb) {
  const int slot = ((cb >> 4) + row) & 7;
  return *(const bf16x8*)((const char*)half + row * 128 + slot * 16);
}

// XCD-aware bijective block swizzle; requires (gridDim.x*gridDim.y) % 8 == 0
__device__ __forceinline__ int xcd_swz(int gx, int gy) {
  int bid = blockIdx.y * gx + blockIdx.x;
  const int nwg = gx * gy;
  return (bid & 7) * (nwg >> 3) + (bid >> 3);
}

// ---------------------------------------------------------------------------
// 4b) 256x256 8-phase GEMM (rotate swizzle + counted vmcnt + setprio).
//     512 threads = 8 waves (2M x 4N), per-wave 128x64 output, BK=64,
//     double-buffered 128 KiB LDS. Grid (N/256, M/256), nwg % 8 == 0.
//     (round-3 verified: out-GEMM < 45.6 us)
// ---------------------------------------------------------------------------
__global__ __launch_bounds__(512, 2) void gemm256(const __bf16* __restrict__ A,
                                                  const __bf16* __restrict__ Bt,
                                                  void* __restrict__ Cv,
                                                  int M, int N, int K, float alpha,
                                                  int cF, const unsigned short* __restrict__ lnw) {
  __shared__ __bf16 lds[8][128 * 64];  // [buf*4 + {A0,A1,B0,B1}] = 128 KiB
  const int tid = threadIdx.x;
  const int wave = tid >> 6, lane = tid & 63;
  const int wm = wave >> 2, wn = wave & 3;  // 2 x 4 wave grid
  const int lr = lane & 15, qd = lane >> 4;
  const int gx = gridDim.x;
  const int bid = xcd_swz(gx, gridDim.y);
  const int bm0 = (bid / gx) * 256, bn0 = (bid % gx) * 256;
  const int nt = K >> 6;

  int rS[2], cS[2];
#pragma unroll
  for (int q = 0; q < 2; ++q) {
    int u = q * 512 + tid;
    rS[q] = u >> 3;
    cS[q] = (((u & 7) - (u >> 3)) & 7) * 8;
  }
  const __bf16* sA[2][2];
  const __bf16* sB[2][2];
#pragma unroll
  for (int h = 0; h < 2; ++h)
#pragma unroll
    for (int q = 0; q < 2; ++q) {
      sA[h][q] = A + (size_t)(bm0 + h * 128 + rS[q]) * K + cS[q];
      sB[h][q] = Bt + (size_t)(bn0 + h * 128 + rS[q]) * K + cS[q];
    }
  const int d0 = tid * 16, d1 = (512 + tid) * 16;

#define STG(sp, half, k)                         \
  do {                                           \
    async16((sp)[0] + (k), (char*)(half) + d0);  \
    async16((sp)[1] + (k), (char*)(half) + d1);  \
  } while (0)

  STG(sB[0], lds[2], 0);
  STG(sA[0], lds[0], 0);
  STG(sB[1], lds[3], 0);
  STG(sA[1], lds[1], 0);
  if (nt > 1) {
    STG(sB[0], lds[6], 64);
    STG(sA[0], lds[4], 64);
    asm volatile("s_waitcnt vmcnt(4)" ::: "memory");
  } else {
    asm volatile("s_waitcnt vmcnt(0)" ::: "memory");
  }
  __builtin_amdgcn_sched_barrier(0);
  __builtin_amdgcn_s_barrier();

  f32x4 acc[8][4] = {};
  bf16x8 af[4][2], bf[4][2];
  const int brow = (wn & 1) * 64;

  for (int t = 0; t < nt; ++t) {
    const int bs = (t & 1) << 2, nb = bs ^ 4;
    const __bf16* myA = lds[bs + wm];
    const __bf16* myB = lds[bs + 2 + (wn >> 1)];
    const int k1 = (t + 1) << 6, k2 = (t + 2) << 6;

    // phase 1
#pragma unroll
    for (int m = 0; m < 4; ++m)
#pragma unroll
      for (int ks = 0; ks < 2; ++ks)
        af[m][ks] = fragld(myA, m * 16 + lr, ks * 64 + qd * 16);
#pragma unroll
    for (int n = 0; n < 2; ++n)
#pragma unroll
      for (int ks = 0; ks < 2; ++ks)
        bf[n][ks] = fragld(myB, brow + n * 16 + lr, ks * 64 + qd * 16);
    if (t + 1 < nt) STG(sB[1], lds[nb + 3], k1);
    __builtin_amdgcn_s_barrier();
    __builtin_amdgcn_s_setprio(1);
#pragma unroll
    for (int m = 0; m < 4; ++m)
#pragma unroll
      for (int n = 0; n < 2; ++n)
#pragma unroll
        for (int ks = 0; ks < 2; ++ks)
          acc[m][n] =
              __builtin_amdgcn_mfma_f32_16x16x32_bf16(af[m][ks], bf[n][ks], acc[m][n], 0, 0, 0);
    __builtin_amdgcn_s_setprio(0);
    __builtin_amdgcn_s_barrier();

    // phase 2
#pragma unroll
    for (int n = 0; n < 2; ++n)
#pragma unroll
      for (int ks = 0; ks < 2; ++ks)
        bf[2 + n][ks] = fragld(myB, brow + (2 + n) * 16 + lr, ks * 64 + qd * 16);
    if (t + 1 < nt) STG(sA[1], lds[nb + 1], k1);
    __builtin_amdgcn_s_barrier();
    __builtin_amdgcn_s_setprio(1);
#pragma unroll
    for (int m = 0; m < 4; ++m)
#pragma unroll
      for (int n = 0; n < 2; ++n)
#pragma unroll
        for (int ks = 0; ks < 2; ++ks)
          acc[m][2 + n] = __builtin_amdgcn_mfma_f32_16x16x32_bf16(af[m][ks], bf[2 + n][ks],
                                                                  acc[m][2 + n], 0, 0, 0);
    __builtin_amdgcn_s_setprio(0);
    __builtin_amdgcn_s_barrier();

    // phase 3
#pragma unroll
    for (int m = 0; m < 4; ++m)
#pragma unroll
      for (int ks = 0; ks < 2; ++ks)
        af[m][ks] = fragld(myA, 64 + m * 16 + lr, ks * 64 + qd * 16);
    if (t + 2 < nt) STG(sB[0], lds[bs + 2], k2);
    __builtin_amdgcn_s_barrier();
    __builtin_amdgcn_s_setprio(1);
#pragma unroll
    for (int m = 0; m < 4; ++m)
#pragma unroll
      for (int n = 0; n < 2; ++n)
#pragma unroll
        for (int ks = 0; ks < 2; ++ks)
          acc[4 + m][2 + n] = __builtin_amdgcn_mfma_f32_16x16x32_bf16(
              af[m][ks], bf[2 + n][ks], acc[4 + m][2 + n], 0, 0, 0);
    __builtin_amdgcn_s_setprio(0);
    __builtin_amdgcn_s_barrier();

    // phase 4
    if (t + 2 < nt) STG(sA[0], lds[bs + 0], k2);
    __builtin_amdgcn_s_barrier();
    __builtin_amdgcn_s_setprio(1);
#pragma unroll
    for (int m = 0; m < 4; ++m)
#pragma unroll
      for (int n = 0; n < 2; ++n)
#pragma unroll
        for (int ks = 0; ks < 2; ++ks)
          acc[4 + m][n] = __builtin_amdgcn_mfma_f32_16x16x32_bf16(af[m][ks], bf[n][ks],
                                                                  acc[4 + m][n], 0, 0, 0);
    __builtin_amdgcn_s_setprio(0);
    if (t + 2 < nt) {
      asm volatile("s_waitcnt vmcnt(4)" ::: "memory");
    } else {
      asm volatile("s_waitcnt vmcnt(0)" ::: "memory");
    }
    __builtin_amdgcn_sched_barrier(0);
    __builtin_amdgcn_s_barrier();
  }
#undef STG

  const bool f32out = cF && !is_bf16(lnw);
  if (!f32out) {
    __bf16* C = (__bf16*)Cv;
#pragma unroll
    for (int m = 0; m < 8; ++m)
#pragma unroll
      for (int n = 0; n < 4; ++n)
#pragma unroll
        for (int r = 0; r < 4; ++r) {
          int grow = bm0 + wm * 128 + m * 16 + qd * 4 + r;
          int gcol = bn0 + wn * 64 + n * 16 + lr;
          C[(size_t)grow * N + gcol] = (__bf16)(acc[m][n][r] * alpha);
        }
  } else {
    float* C = (float*)Cv;
#pragma unroll
    for (int m = 0; m < 8; ++m)
#pragma unroll
      for (int n = 0; n < 4; ++n)
#pragma unroll
        for (int r = 0; r < 4; ++r) {
          int grow = bm0 + wm * 128 + m * 16 + qd * 4 + r;
          int gcol = bn0 + wn * 64 + n * 16 + lr;
          C[(size_t)grow * N + gcol] = acc[m][n][r] * alpha;
        }
  }
}

// ---------------------------------------------------------------------------
// 4c) 256x128 4-phase GEMM for tall-skinny outputs (q-GEMM: N=1024).
//     512 threads = 8 waves (4M x 2N), per-wave 64x64, BK=64.
//     LDS: 2 buf x {A0,A1,B} x 16 KiB = 96 KiB. Grid (N/128, M/256).
//     (round-3 verified: 45.8 us, 0 bank conflicts)
// ---------------------------------------------------------------------------
__global__ __launch_bounds__(512, 2) void gemm256x128(const __bf16* __restrict__ A,
                                                      const __bf16* __restrict__ Bt,
                                                      void* __restrict__ Cv,
                                                      int M, int N, int K, float alpha,
                                                      int cF, const unsigned short* __restrict__ lnw) {
  __shared__ __bf16 lds[6][128 * 64];  // [buf*3 + {A0,A1,B}] = 96 KiB
  const int tid = threadIdx.x;
  const int wave = tid >> 6, lane = tid & 63;
  const int wm = wave >> 1, wn = wave & 1;  // 4M x 2N wave grid; per-wave 64x64
  const int lr = lane & 15, qd = lane >> 4;
  const int gx = gridDim.x;
  const int bid = xcd_swz(gx, gridDim.y);
  const int bm0 = (bid / gx) * 256, bn0 = (bid % gx) * 128;
  const int nt = K >> 6;

  int rS[2], cS[2];
#pragma unroll
  for (int q = 0; q < 2; ++q) {
    int u = q * 512 + tid;
    rS[q] = u >> 3;
    cS[q] = (((u & 7) - (u >> 3)) & 7) * 8;
  }
  const __bf16* sA0[2];
  const __bf16* sA1[2];
  const __bf16* sB[2];
#pragma unroll
  for (int q = 0; q < 2; ++q) {
    sA0[q] = A + (size_t)(bm0 + rS[q]) * K + cS[q];
    sA1[q] = A + (size_t)(bm0 + 128 + rS[q]) * K + cS[q];
    sB[q]  = Bt + (size_t)(bn0 + rS[q]) * K + cS[q];
  }
  const int d0 = tid * 16, d1 = (512 + tid) * 16;

#define STG(sp, half, k)                         \
  do {                                           \
    async16((sp)[0] + (k), (char*)(half) + d0);  \
    async16((sp)[1] + (k), (char*)(half) + d1);  \
  } while (0)

  STG(sB,  lds[2], 0);
  STG(sA1, lds[1], 0);
  STG(sA0, lds[0], 0);
  if (nt > 1) {
    STG(sA0, lds[3], 64);
    asm volatile("s_waitcnt vmcnt(2)" ::: "memory");
  } else {
    asm volatile("s_waitcnt vmcnt(0)" ::: "memory");
  }
  __builtin_amdgcn_sched_barrier(0);
  __builtin_amdgcn_s_barrier();

  f32x4 acc[4][4] = {};
  bf16x8 af[2][2], bf[4][2];
  const int arow = (wm & 1) * 64, brow = wn * 64;

  for (int t = 0; t < nt; ++t) {
    const int bs = (t & 1) * 3, nb = bs ^ 3;
    const __bf16* myA = lds[bs + (wm >> 1)];
    const __bf16* myB = lds[bs + 2];
    const int k1 = (t + 1) << 6, k2 = (t + 2) << 6;

    // phase 1
#pragma unroll
    for (int m = 0; m < 2; ++m)
#pragma unroll
      for (int ks = 0; ks < 2; ++ks)
        af[m][ks] = fragld(myA, arow + m * 16 + lr, ks * 64 + qd * 16);
#pragma unroll
    for (int n = 0; n < 2; ++n)
#pragma unroll
      for (int ks = 0; ks < 2; ++ks)
        bf[n][ks] = fragld(myB, brow + n * 16 + lr, ks * 64 + qd * 16);
    if (t + 1 < nt) STG(sB, lds[nb + 2], k1);
    __builtin_amdgcn_s_barrier();
    __builtin_amdgcn_s_setprio(1);
#pragma unroll
    for (int m = 0; m < 2; ++m)
#pragma unroll
      for (int n = 0; n < 2; ++n)
#pragma unroll
        for (int ks = 0; ks < 2; ++ks)
          acc[m][n] =
              __builtin_amdgcn_mfma_f32_16x16x32_bf16(af[m][ks], bf[n][ks], acc[m][n], 0, 0, 0);
    __builtin_amdgcn_s_setprio(0);
    __builtin_amdgcn_s_barrier();

    // phase 2
#pragma unroll
    for (int n = 0; n < 2; ++n)
#pragma unroll
      for (int ks = 0; ks < 2; ++ks)
        bf[2 + n][ks] = fragld(myB, brow + (2 + n) * 16 + lr, ks * 64 + qd * 16);
    if (t + 1 < nt) STG(sA1, lds[nb + 1], k1);
    __builtin_amdgcn_s_barrier();
    __builtin_amdgcn_s_setprio(1);
#pragma unroll
    for (int m = 0; m < 2; ++m)
#pragma unroll
      for (int n = 0; n < 2; ++n)
#pragma unroll
        for (int ks = 0; ks < 2; ++ks)
          acc[m][2 + n] = __builtin_amdgcn_mfma_f32_16x16x32_bf16(af[m][ks], bf[2 + n][ks],
                                                                  acc[m][2 + n], 0, 0, 0);
    __builtin_amdgcn_s_setprio(0);
    __builtin_amdgcn_s_barrier();

    // phase 3
#pragma unroll
    for (int m = 0; m < 2; ++m)
#pragma unroll
      for (int ks = 0; ks < 2; ++ks)
        af[m][ks] = fragld(myA, arow + 32 + m * 16 + lr, ks * 64 + qd * 16);
    __builtin_amdgcn_s_barrier();
    __builtin_amdgcn_s_setprio(1);
#pragma unroll
    for (int m = 0; m < 2; ++m)
#pragma unroll
      for (int n = 0; n < 2; ++n)
#pragma unroll
        for (int ks = 0; ks < 2; ++ks)
          acc[2 + m][2 + n] = __builtin_amdgcn_mfma_f32_16x16x32_bf16(
              af[m][ks], bf[2 + n][ks], acc[2 + m][2 + n], 0, 0, 0);
    __builtin_amdgcn_s_setprio(0);
    __builtin_amdgcn_s_barrier();

    // phase 4
    if (t + 2 < nt) STG(sA0, lds[bs + 0], k2);
    __builtin_amdgcn_s_barrier();
    __builtin_amdgcn_s_setprio(1);
#pragma unroll
    for (int m = 0; m < 2; ++m)
#pragma unroll
      for (int n = 0; n < 2; ++n)
#pragma unroll
        for (int ks = 0; ks < 2; ++ks)
          acc[2 + m][n] = __builtin_amdgcn_mfma_f32_16x16x32_bf16(af[m][ks], bf[n][ks],
                                                                  acc[2 + m][n], 0, 0, 0);
    __builtin_amdgcn_s_setprio(0);
    if (t + 2 < nt) {
      asm volatile("s_waitcnt vmcnt(2)" ::: "memory");
    } else {
      asm volatile("s_waitcnt vmcnt(0)" ::: "memory");
    }
    __builtin_amdgcn_sched_barrier(0);
    __builtin_amdgcn_s_barrier();
  }
#undef STG

  const bool f32out = cF && !is_bf16(lnw);
  if (!f32out) {
    __bf16* C = (__bf16*)Cv;
#pragma unroll
    for (int m = 0; m < 4; ++m)
#pragma unroll
      for (int n = 0; n < 4; ++n)
#pragma unroll
        for (int r = 0; r < 4; ++r) {
          int grow = bm0 + wm * 64 + m * 16 + qd * 4 + r;
          int gcol = bn0 + wn * 64 + n * 16 + lr;
          C[(size_t)grow * N + gcol] = (__bf16)(acc[m][n][r] * alpha);
        }
  } else {
    float* C = (float*)Cv;
#pragma unroll
    for (int m = 0; m < 4; ++m)
#pragma unroll
      for (int n = 0; n < 4; ++n)
#pragma unroll
        for (int r = 0; r < 4; ++r) {
          int grow = bm0 + wm * 64 + m * 16 + qd * 4 + r;
          int gcol = bn0 + wn * 64 + n * 16 + lr;
          C[(size_t)grow * N + gcol] = acc[m][n][r] * alpha;
        }
  }
}

// ---------------------------------------------------------------------------
// 5) MFMA attention (unchanged — verified correct)
// ---------------------------------------------------------------------------
__global__ __launch_bounds__(256) void attn_kernel(const __bf16* __restrict__ q,
                                                   const __bf16* __restrict__ kv,
                                                   const int* __restrict__ chunk,
                                                   __bf16* __restrict__ attn) {
  const int h = blockIdx.x, tile = blockIdx.y, b = blockIdx.z;
  const int tid = threadIdx.x, wave = tid >> 6, lane = tid & 63;
  const int lr = lane & 15, qd = lane >> 4;
  __shared__ __bf16 Vt[64][72];
  __shared__ __bf16 P[4][64][72];

  int c = chunk[b * T_DIM + tile * 256];
  c = c < 0 ? 0 : (c > 7 ? 7 : c);
  const size_t kvbase = ((size_t)b * J_TOK + c * 64) * (2 * INNER_D);

#pragma unroll
  for (int it = 0; it < 2; ++it) {
    int u = it * 256 + tid;
    int key = u & 63, d0 = (u >> 6) * 8;
    bf16x8 v = __builtin_bit_cast(
        bf16x8, *(const i32x4*)(kv + kvbase + (size_t)key * (2 * INNER_D) + INNER_D + h * 64 + d0));
#pragma unroll
    for (int j = 0; j < 8; ++j) Vt[d0 + j][key] = v[j];
  }
  __syncthreads();

  const size_t qbase = ((size_t)(b * T_DIM + tile * 256 + wave * 64)) * INNER_D + h * 64;
  f32x4 acc[4][4] = {};
#pragma unroll
  for (int ks = 0; ks < 2; ++ks) {
    bf16x8 af[4], bf[4];
#pragma unroll
    for (int mt = 0; mt < 4; ++mt)
      af[mt] = __builtin_bit_cast(
          bf16x8, *(const i32x4*)(q + qbase + (size_t)(mt * 16 + lr) * INNER_D + ks * 32 + qd * 8));
#pragma unroll
    for (int nt = 0; nt < 4; ++nt)
      bf[nt] = __builtin_bit_cast(
          bf16x8,
          *(const i32x4*)(kv + kvbase + (size_t)(nt * 16 + lr) * (2 * INNER_D) + h * 64 + ks * 32 + qd * 8));
#pragma unroll
    for (int mt = 0; mt < 4; ++mt)
#pragma unroll
      for (int nt = 0; nt < 4; ++nt)
        acc[mt][nt] =
            __builtin_amdgcn_mfma_f32_16x16x32_bf16(af[mt], bf[nt], acc[mt][nt], 0, 0, 0);
  }

#pragma unroll
  for (int mt = 0; mt < 4; ++mt) {
#pragma unroll
    for (int r = 0; r < 4; ++r) {
      float v0 = acc[mt][0][r], v1 = acc[mt][1][r], v2 = acc[mt][2][r], v3 = acc[mt][3][r];
      float mx = fmaxf(fmaxf(v0, v1), fmaxf(v2, v3));
      mx = fmaxf(mx, __shfl_xor(mx, 1));
      mx = fmaxf(mx, __shfl_xor(mx, 2));
      mx = fmaxf(mx, __shfl_xor(mx, 4));
      mx = fmaxf(mx, __shfl_xor(mx, 8));
      float p0 = __expf(v0 - mx), p1 = __expf(v1 - mx), p2 = __expf(v2 - mx), p3 = __expf(v3 - mx);
      float l = p0 + p1 + p2 + p3;
      l += __shfl_xor(l, 1);
      l += __shfl_xor(l, 2);
      l += __shfl_xor(l, 4);
      l += __shfl_xor(l, 8);
      const float rl = 1.0f / l;
      const int row = mt * 16 + qd * 4 + r;
      P[wave][row][lr]      = (__bf16)(p0 * rl);
      P[wave][row][16 + lr] = (__bf16)(p1 * rl);
      P[wave][row][32 + lr] = (__bf16)(p2 * rl);
      P[wave][row][48 + lr] = (__bf16)(p3 * rl);
    }
  }
  __syncthreads();

  f32x4 oc[4][4] = {};
#pragma unroll
  for (int ks = 0; ks < 2; ++ks) {
    bf16x8 af[4], bv[4];
#pragma unroll
    for (int mt = 0; mt < 4; ++mt)
      af[mt] = *(const bf16x8*)&P[wave][mt * 16 + lr][ks * 32 + qd * 8];
#pragma unroll
    for (int nt = 0; nt < 4; ++nt)
      bv[nt] = *(const bf16x8*)&Vt[nt * 16 + lr][ks * 32 + qd * 8];
#pragma unroll
    for (int mt = 0; mt < 4; ++mt)
#pragma unroll
      for (int nt = 0; nt < 4; ++nt)
        oc[mt][nt] =
            __builtin_amdgcn_mfma_f32_16x16x32_bf16(af[mt], bv[nt], oc[mt][nt], 0, 0, 0);
  }

#pragma unroll
  for (int mt = 0; mt < 4; ++mt)
#pragma unroll
    for (int nt = 0; nt < 4; ++nt)
#pragma unroll
      for (int r = 0; r < 4; ++r) {
        int row = mt * 16 + qd * 4 + r;
        int col = nt * 16 + lr;
        attn[((size_t)(b * T_DIM + tile * 256 + wave * 64 + row)) * INNER_D + h * 64 + col] =
            (__bf16)oc[mt][nt][r];
      }
}

// ---------------------------------------------------------------------------
// launch: 5 dispatches (ext workspace) or 7 (fallback, round-3 layout)
// ---------------------------------------------------------------------------
extern "C" void kernel_launch(void* const* d_in, const int* in_sizes, int n_in,
                              void* d_out, int out_size, void* d_ws, size_t ws_size,
                              hipStream_t stream) {
  const void* y     = d_in[0];
  const void* media = d_in[1];
  const int*  mloc  = (const int*)d_in[2];
  const unsigned short* lnw = (const unsigned short*)d_in[3];
  const void* lnb   = d_in[4];
  const void* Wq    = d_in[5];
  const void* Wkv   = d_in[6];
  const void* Wout  = d_in[7];

  char* ws = (char*)d_ws;
  int*    chunk = (int*)ws;                                 // 64 KB
  __bf16* yn    = (__bf16*)(ws + 65536);                    // 33.55 MB [8192,2048]
  __bf16* attn  = yn;                                       // alias (yn dead after q-gemm)
  __bf16* q     = (__bf16*)(ws + 65536 + 33554432);         // 16.78 MB
  __bf16* kv    = (__bf16*)(ws + 65536 + 33554432 + 16777216);           // 8.39 MB
  __bf16* WqT   = (__bf16*)(ws + 65536 + 33554432 + 16777216 + 8388608); // 4.19 MB
  // base total: 62.98 MB. Extended adds media_bf/WkvT/WoutT (12.58 MB).
  const size_t EXT_NEED = 75563008;  // 62.98 MB + 3 x 4.19 MB

  if (ws_size >= EXT_NEED) {
    __bf16* media_bf = (__bf16*)(ws + 62980096);
    __bf16* WkvT     = (__bf16*)(ws + 67174400);
    __bf16* WoutT    = (__bf16*)(ws + 71368704);
    // 1) fused prep: scan | media->bf16 | T(Wkv) | T(Wq) | T(Wout) | LN
    prep_kernel<<<4 + 1024 + 2048 + 2048 + 2048 + 8192, 256, 0, stream>>>(
        mloc, chunk, media, media_bf, Wkv, WkvT, Wq, WqT,
        Wout, WoutT, y, lnb, yn, 2048, lnw);
    // 2) kv = media_bf @ Wkv
    gemm_bt<<<dim3(16, 16), 256, 0, stream>>>(media_bf, WkvT, kv, 2048, 2048, 1024, 1.0f, 0, lnw);
    // 3) q = yn @ Wq * 0.125
    gemm256x128<<<dim3(8, 32), 512, 0, stream>>>(yn, WqT, q, 8192, 1024, 2048, 0.125f, 0, lnw);
    // 4) attention (attn aliases yn — dead after q-gemm)
    attn_kernel<<<dim3(16, 8, 4), 256, 0, stream>>>(q, kv, chunk, attn);
    // 5) out = attn @ Wout
    gemm256<<<dim3(8, 32), 512, 0, stream>>>(attn, WoutT, d_out, 8192, 2048, 1024, 1.0f, 1, lnw);
  } else {
    // fallback: round-3 aliased layout, 7 dispatches
    __bf16* media_bf = yn;                                  // alias (dead before LN)
    __bf16* WkvT     = (__bf16*)(ws + 65536 + 4194304);     // alias in yn
    __bf16* WoutT    = q;                                   // alias (q dead after attn)
    prep_kernel<<<4 + 1024 + 2048 + 2048, 256, 0, stream>>>(
        mloc, chunk, media, media_bf, Wkv, WkvT, Wq, WqT,
        Wout, WoutT, y, lnb, yn, 0, lnw);
    gemm_bt<<<dim3(16, 16), 256, 0, stream>>>(media_bf, WkvT, kv, 2048, 2048, 1024, 1.0f, 0, lnw);
    ln_kernel<<<BATCH * T_DIM, 256, 0, stream>>>(y, lnw, lnb, yn);
    gemm256x128<<<dim3(8, 32), 512, 0, stream>>>(yn, WqT, q, 8192, 1024, 2048, 0.125f, 0, lnw);
    attn_kernel<<<dim3(16, 8, 4), 256, 0, stream>>>(q, kv, chunk, attn);
    transpose_kernel<<<dim3(64, 32), 256, 0, stream>>>(Wout, WoutT, 1024, 2048, lnw);
    gemm256<<<dim3(8, 32), 512, 0, stream>>>(attn, WoutT, d_out, 8192, 2048, 1024, 1.0f, 1, lnw);
  }
}